// Round 2
// baseline (741.722 us; speedup 1.0000x reference)
//
#include <hip/hip_runtime.h>

// PairwiseMLPLinkPredictor on MI355X (gfx950)
// feats = bf16(x[u]) * bf16(x[v]);  h1 = relu(feats@W1+b1);  h2 = relu(h1@W2+b2);
// out = h2@W3 + b3.   GEMM1/2 via v_mfma_f32_16x16x32_bf16, layer 3 fused in epilogue.
//
// R1: latency-bound fix. 1024-thread blocks, MT=64, column-sliced waves so the
// accumulator is only 4-6 floatx4/thread (R0 had 16 -> 64 AGPRs -> 4 waves/SIMD).
// Target: 2 blocks x 16 waves = 32 waves/CU (100% occupancy), LDS 32 KB/block.

typedef __attribute__((ext_vector_type(8))) short short8;   // 8 bf16 = 4 VGPRs
typedef __attribute__((ext_vector_type(4))) float floatx4;  // MFMA C/D frag

#define MT 64         // pairs per block
#define NTHREADS 1024 // 16 waves

__device__ __forceinline__ unsigned short f2bf(float f) {
  union { float f; unsigned u; } a; a.f = f;
  unsigned r = a.u + 0x7FFFu + ((a.u >> 16) & 1u);   // round-to-nearest-even
  return (unsigned short)(r >> 16);
}

// ---------- prologue: x -> bf16 table ----------
__global__ void cast_x_kernel(const float* __restrict__ x, unsigned short* __restrict__ xb, int n4) {
  int i = blockIdx.x * blockDim.x + threadIdx.x;
  if (i >= n4) return;
  float4 v = ((const float4*)x)[i];
  ushort4 o;
  o.x = f2bf(v.x); o.y = f2bf(v.y); o.z = f2bf(v.z); o.w = f2bf(v.w);
  ((ushort4*)xb)[i] = o;
}

// ---------- prologue: W1 [256,256] / W2 [256,128] -> bf16, transposed to [n][k] ----------
__global__ void prep_w_kernel(const float* __restrict__ W1, const float* __restrict__ W2,
                              unsigned short* __restrict__ w1t, unsigned short* __restrict__ w2t) {
  int i = blockIdx.x * blockDim.x + threadIdx.x;
  if (i < 256 * 256) {
    int k = i >> 8, n = i & 255;
    w1t[n * 256 + k] = f2bf(W1[k * 256 + n]);
  } else {
    int j = i - 256 * 256;
    if (j < 128 * 256) {
      int k = j >> 7, n = j & 127;
      w2t[n * 256 + k] = f2bf(W2[k * 128 + n]);
    }
  }
}

// ---------- fused pairwise MLP ----------
// LDS buf0: 64 rows x 256 bf16 = 32 KB. Row stride 512 B; 16B chunks XOR-swizzled
// by (row & 15) so stride-512 A-fragment ds_read_b128 is conflict-free.
__global__ __launch_bounds__(NTHREADS, 8) void mlp_kernel(
    const unsigned short* __restrict__ xb,
    const unsigned short* __restrict__ w1t,
    const unsigned short* __restrict__ w2t,
    const float* __restrict__ b1,
    const float* __restrict__ b2,
    const float* __restrict__ w3,
    const float* __restrict__ b3,
    const int* __restrict__ ep,
    float* __restrict__ out,
    int E)
{
  __shared__ __align__(16) unsigned short buf0[MT * 256];  // 32768 B
  __shared__ float ss[MT];                                 // layer-3 partial sums

  const int tid  = threadIdx.x;
  const int wv   = tid >> 6;      // 0..15
  const int lane = tid & 63;
  const int q    = lane >> 4;     // quad 0..3
  const int r16  = lane & 15;
  const int row0 = blockIdx.x * MT;
  char* const ldsb = (char*)buf0;

  if (tid < MT) ss[tid] = 0.f;

  // ---- gather + elementwise product -> feats in LDS (2 passes, 4 loads/thread) ----
  {
    const int c    = tid & 31;    // 16B chunk within the 512B row
    const int mrow = tid >> 5;    // 0..31
    #pragma unroll
    for (int pass = 0; pass < 2; ++pass) {
      int m = pass * 32 + mrow;
      int g = row0 + m;
      int u = 0, v = 0;
      if (g < E) { u = ep[2 * g]; v = ep[2 * g + 1]; }
      uint4 a = *(const uint4*)(xb + ((size_t)u << 8) + (c << 3));
      uint4 b = *(const uint4*)(xb + ((size_t)v << 8) + (c << 3));
      const unsigned* au = &a.x;
      const unsigned* bu = &b.x;
      uint4 pv;
      unsigned* po = &pv.x;
      #pragma unroll
      for (int t = 0; t < 4; ++t) {
        unsigned ua = au[t], ub = bu[t];
        float lo = __uint_as_float(ua << 16)          * __uint_as_float(ub << 16);
        float hi = __uint_as_float(ua & 0xFFFF0000u) * __uint_as_float(ub & 0xFFFF0000u);
        po[t] = (unsigned)f2bf(lo) | ((unsigned)f2bf(hi) << 16);
      }
      int cp = c ^ (m & 15);                       // swizzle
      *(uint4*)(ldsb + m * 512 + (cp << 4)) = pv;
    }
  }
  __syncthreads();

  // ---- GEMM1: h1 = relu(feats @ W1 + b1); wave owns 64 rows x 16 cols ----
  floatx4 acc[4];
  #pragma unroll
  for (int i = 0; i < 4; ++i) acc[i] = (floatx4){0.f, 0.f, 0.f, 0.f};

  char* const abase = ldsb + r16 * 512;
  const unsigned short* const brow = w1t + (wv * 16 + r16) * 256 + q * 8;

  #pragma unroll
  for (int kt = 0; kt < 8; ++kt) {
    const int aoff = (kt << 6) ^ ((q ^ r16) << 4);   // swizzled A chunk
    short8 av[4], bv;
    #pragma unroll
    for (int mt = 0; mt < 4; ++mt)
      av[mt] = *(const short8*)(abase + mt * (16 * 512) + aoff);
    bv = *(const short8*)(brow + kt * 32);
    #pragma unroll
    for (int mt = 0; mt < 4; ++mt)
      acc[mt] = __builtin_amdgcn_mfma_f32_16x16x32_bf16(av[mt], bv, acc[mt], 0, 0, 0);
  }

  __syncthreads();   // all waves done reading feats

  // ---- writeback h1 (bias+relu, bf16) into buf0, swizzled ----
  {
    const float bias1 = b1[wv * 16 + r16];
    const int n = wv * 16 + r16;                 // C/D: col = lane&15
    #pragma unroll
    for (int mt = 0; mt < 4; ++mt) {
      #pragma unroll
      for (int r = 0; r < 4; ++r) {
        int mlo = q * 4 + r;                     // C/D: row = 4*quad + reg
        int m = mt * 16 + mlo;
        float h = fmaxf(acc[mt][r] + bias1, 0.f);
        int ch = (n >> 3) ^ mlo;
        *(unsigned short*)(ldsb + m * 512 + (ch << 4) + ((n & 7) << 1)) = f2bf(h);
      }
    }
  }
  __syncthreads();

  // ---- GEMM2: h2 = relu(h1 @ W2 + b2); wave owns 32 rows x 16 cols ----
  const int mg2 = wv >> 3;        // 0..1: 32-row slab
  const int ng2 = wv & 7;         // 0..7: 16-col slab
  floatx4 acc2[2];
  acc2[0] = (floatx4){0.f, 0.f, 0.f, 0.f};
  acc2[1] = (floatx4){0.f, 0.f, 0.f, 0.f};

  char* const abase2 = ldsb + (mg2 * 32 + r16) * 512;
  const unsigned short* const b2row = w2t + (ng2 * 16 + r16) * 256 + q * 8;

  #pragma unroll
  for (int kt = 0; kt < 8; ++kt) {
    const int aoff = (kt << 6) ^ ((q ^ r16) << 4);
    short8 av[2], bv;
    av[0] = *(const short8*)(abase2 + aoff);
    av[1] = *(const short8*)(abase2 + 16 * 512 + aoff);
    bv = *(const short8*)(b2row + kt * 32);
    acc2[0] = __builtin_amdgcn_mfma_f32_16x16x32_bf16(av[0], bv, acc2[0], 0, 0, 0);
    acc2[1] = __builtin_amdgcn_mfma_f32_16x16x32_bf16(av[1], bv, acc2[1], 0, 0, 0);
  }

  // ---- fused layer 3: scores[m] += sum_n relu(h2[m][n]) * W3[n] ----
  {
    const float b2v = b2[ng2 * 16 + r16];
    const float w3v = w3[ng2 * 16 + r16];
    #pragma unroll
    for (int mt = 0; mt < 2; ++mt) {
      #pragma unroll
      for (int r = 0; r < 4; ++r) {
        float h = fmaxf(acc2[mt][r] + b2v, 0.f);
        float p = h * w3v;
        p += __shfl_xor(p, 1);
        p += __shfl_xor(p, 2);
        p += __shfl_xor(p, 4);
        p += __shfl_xor(p, 8);
        if (r16 == 0) atomicAdd(&ss[mg2 * 32 + mt * 16 + q * 4 + r], p);
      }
    }
  }
  __syncthreads();

  if (tid < MT) {
    int g = row0 + tid;
    if (g < E) out[g] = ss[tid] + b3[0];
  }
}

extern "C" void kernel_launch(void* const* d_in, const int* in_sizes, int n_in,
                              void* d_out, int out_size, void* d_ws, size_t ws_size,
                              hipStream_t stream) {
  const float* x  = (const float*)d_in[0];
  const float* W1 = (const float*)d_in[1];
  const float* b1 = (const float*)d_in[2];
  const float* W2 = (const float*)d_in[3];
  const float* b2 = (const float*)d_in[4];
  const float* W3 = (const float*)d_in[5];
  const float* b3 = (const float*)d_in[6];
  // d_in[7] = edge_index (unused by the reference computation)
  const int*   ep = (const int*)d_in[8];
  float* out = (float*)d_out;

  const int NX = in_sizes[0];        // 100000*256 = 25,600,000
  const int E  = in_sizes[8] / 2;    // 1,000,000

  // workspace layout: xb (NX bf16) | w1t (256*256 bf16) | w2t (128*256 bf16)  ~49 MB
  unsigned short* xb  = (unsigned short*)d_ws;
  unsigned short* w1t = (unsigned short*)((char*)d_ws + (size_t)NX * 2);
  unsigned short* w2t = w1t + 256 * 256;

  cast_x_kernel<<<(NX / 4 + 255) / 256, 256, 0, stream>>>(x, xb, NX / 4);
  prep_w_kernel<<<(256 * 256 + 128 * 256 + 255) / 256, 256, 0, stream>>>(W1, W2, w1t, w2t);
  mlp_kernel<<<(E + MT - 1) / MT, NTHREADS, 0, stream>>>(xb, w1t, w2t, b1, b2, W3, b3, ep, out, E);
}

// Round 3
// 664.849 us; speedup vs baseline: 1.1156x; 1.1156x over previous
//
#include <hip/hip_runtime.h>

// PairwiseMLPLinkPredictor on MI355X (gfx950)
// feats = bf16(x[u]) * bf16(x[v]);  h1 = relu(feats@W1+b1);  h2 = relu(h1@W2+b2);
// out = h2@W3 + b3.   GEMM1/2 via v_mfma_f32_16x16x32_bf16, layer 3 fused in epilogue.
//
// R2: back to R0 blocking (MT=128, 8 waves, 4x4 frags — 555 us) + non-temporal
// gather/ep loads so the 1 GB random gather stream stops evicting the 192 KB of
// weights from L2 (theory: B-frag loads were L3-latency-bound due to L2 thrash).

typedef __attribute__((ext_vector_type(8))) short short8;   // 8 bf16 = 4 VGPRs
typedef __attribute__((ext_vector_type(4))) float floatx4;  // MFMA C/D frag
typedef __attribute__((ext_vector_type(4))) unsigned uintx4;
typedef __attribute__((ext_vector_type(2))) int intx2;

#define MT 128        // pairs per block
#define NTHREADS 512  // 8 waves

__device__ __forceinline__ unsigned short f2bf(float f) {
  union { float f; unsigned u; } a; a.f = f;
  unsigned r = a.u + 0x7FFFu + ((a.u >> 16) & 1u);   // round-to-nearest-even
  return (unsigned short)(r >> 16);
}

// ---------- prologue: x -> bf16 table ----------
__global__ void cast_x_kernel(const float* __restrict__ x, unsigned short* __restrict__ xb, int n4) {
  int i = blockIdx.x * blockDim.x + threadIdx.x;
  if (i >= n4) return;
  float4 v = ((const float4*)x)[i];
  ushort4 o;
  o.x = f2bf(v.x); o.y = f2bf(v.y); o.z = f2bf(v.z); o.w = f2bf(v.w);
  ((ushort4*)xb)[i] = o;
}

// ---------- prologue: W1 [256,256] / W2 [256,128] -> bf16, transposed to [n][k] ----------
__global__ void prep_w_kernel(const float* __restrict__ W1, const float* __restrict__ W2,
                              unsigned short* __restrict__ w1t, unsigned short* __restrict__ w2t) {
  int i = blockIdx.x * blockDim.x + threadIdx.x;
  if (i < 256 * 256) {
    int k = i >> 8, n = i & 255;
    w1t[n * 256 + k] = f2bf(W1[k * 256 + n]);
  } else {
    int j = i - 256 * 256;
    if (j < 128 * 256) {
      int k = j >> 7, n = j & 127;
      w2t[n * 256 + k] = f2bf(W2[k * 128 + n]);
    }
  }
}

// ---------- fused pairwise MLP ----------
// LDS buf0: 128 rows x 256 bf16 = 64 KB. 16B chunks XOR-swizzled by (row & 15):
// conflict-free stride-512 ds_read_b128 without padding.
__global__ __launch_bounds__(NTHREADS, 4) void mlp_kernel(
    const unsigned short* __restrict__ xb,
    const unsigned short* __restrict__ w1t,
    const unsigned short* __restrict__ w2t,
    const float* __restrict__ b1,
    const float* __restrict__ b2,
    const float* __restrict__ w3,
    const float* __restrict__ b3,
    const int* __restrict__ ep,
    float* __restrict__ out,
    int E)
{
  __shared__ __align__(16) unsigned short buf0[MT * 256];  // 65536 B
  __shared__ float ss[MT];

  const int tid  = threadIdx.x;
  const int wv   = tid >> 6;
  const int lane = tid & 63;
  const int q    = lane >> 4;     // quad-row 0..3
  const int r16  = lane & 15;
  const int row0 = blockIdx.x * MT;
  char* const ldsb = (char*)buf0;

  if (tid < MT) ss[tid] = 0.f;

  // ---- gather + elementwise product -> feats in LDS (non-temporal streams) ----
  {
    const int c    = tid & 31;    // 16B chunk (32 per 512B row)
    const int mrow = tid >> 5;    // 0..15

    intx2 uv[8];
    #pragma unroll
    for (int pass = 0; pass < 8; ++pass) {
      int g = row0 + pass * 16 + mrow;
      int gg = g < E ? g : 0;
      uv[pass] = __builtin_nontemporal_load((const intx2*)(ep + 2 * (size_t)gg));
    }

    #pragma unroll
    for (int pass = 0; pass < 8; ++pass) {
      int m = pass * 16 + mrow;
      uintx4 a = __builtin_nontemporal_load((const uintx4*)(xb + ((size_t)uv[pass].x << 8) + (c << 3)));
      uintx4 b = __builtin_nontemporal_load((const uintx4*)(xb + ((size_t)uv[pass].y << 8) + (c << 3)));
      uintx4 pv;
      #pragma unroll
      for (int t = 0; t < 4; ++t) {
        unsigned ua = a[t], ub = b[t];
        float lo = __uint_as_float(ua << 16)          * __uint_as_float(ub << 16);
        float hi = __uint_as_float(ua & 0xFFFF0000u) * __uint_as_float(ub & 0xFFFF0000u);
        pv[t] = (unsigned)f2bf(lo) | ((unsigned)f2bf(hi) << 16);
      }
      int cp = c ^ (m & 15);                       // swizzle
      *(uintx4*)(ldsb + m * 512 + (cp << 4)) = pv;
    }
  }
  __syncthreads();

  const int mg = wv >> 2;                 // 0..1: 64-row slab
  const int ng = wv & 3;                  // 0..3: 64-col slab (GEMM1) / 32-col (GEMM2)
  const int swz16 = (q ^ r16) << 4;       // A-frag chunk swizzle, byte units

  // ---- GEMM1: h1 = relu(feats @ W1 + b1), acc 64x64 per wave ----
  floatx4 acc[4][4];
  #pragma unroll
  for (int i = 0; i < 4; ++i)
    #pragma unroll
    for (int j = 0; j < 4; ++j)
      acc[i][j] = (floatx4){0.f, 0.f, 0.f, 0.f};

  char* const arow = ldsb + (mg * 64 + r16) * 512;                        // A row base
  const unsigned short* const brow = w1t + (ng * 64 + r16) * 256 + q * 8; // B base (L2-hot)

  #pragma unroll
  for (int kt = 0; kt < 8; ++kt) {
    short8 av[4], bv[4];
    #pragma unroll
    for (int nt = 0; nt < 4; ++nt)
      bv[nt] = *(const short8*)(brow + nt * (16 * 256) + kt * 32);
    #pragma unroll
    for (int mt = 0; mt < 4; ++mt)
      av[mt] = *(const short8*)(arow + mt * (16 * 512) + ((kt << 6) ^ swz16));
    #pragma unroll
    for (int mt = 0; mt < 4; ++mt)
      #pragma unroll
      for (int nt = 0; nt < 4; ++nt)
        acc[mt][nt] = __builtin_amdgcn_mfma_f32_16x16x32_bf16(av[mt], bv[nt], acc[mt][nt], 0, 0, 0);
  }

  __syncthreads();   // all waves done reading feats

  // ---- writeback h1 (bias+relu, bf16) into buf0, swizzled ----
  {
    float bias1[4];
    #pragma unroll
    for (int nt = 0; nt < 4; ++nt) bias1[nt] = b1[ng * 64 + nt * 16 + r16];
    #pragma unroll
    for (int mt = 0; mt < 4; ++mt) {
      #pragma unroll
      for (int r = 0; r < 4; ++r) {
        int mlo = q * 4 + r;                      // C/D: row = 4*quad + reg
        int m = mg * 64 + mt * 16 + mlo;
        char* rowp = ldsb + m * 512;
        #pragma unroll
        for (int nt = 0; nt < 4; ++nt) {
          int n = ng * 64 + nt * 16 + r16;        // C/D: col = lane&15
          float h = fmaxf(acc[mt][nt][r] + bias1[nt], 0.f);
          int ch = (n >> 3) ^ mlo;
          *(unsigned short*)(rowp + (ch << 4) + ((n & 7) << 1)) = f2bf(h);
        }
      }
    }
  }
  __syncthreads();

  // ---- GEMM2: h2 = relu(h1 @ W2 + b2), acc 64x32 per wave ----
  floatx4 acc2[4][2];
  #pragma unroll
  for (int i = 0; i < 4; ++i) {
    acc2[i][0] = (floatx4){0.f, 0.f, 0.f, 0.f};
    acc2[i][1] = (floatx4){0.f, 0.f, 0.f, 0.f};
  }
  const unsigned short* const b2row = w2t + (ng * 32 + r16) * 256 + q * 8;

  #pragma unroll
  for (int kt = 0; kt < 8; ++kt) {
    short8 av[4], bv[2];
    #pragma unroll
    for (int nt = 0; nt < 2; ++nt)
      bv[nt] = *(const short8*)(b2row + nt * (16 * 256) + kt * 32);
    #pragma unroll
    for (int mt = 0; mt < 4; ++mt)
      av[mt] = *(const short8*)(arow + mt * (16 * 512) + ((kt << 6) ^ swz16));
    #pragma unroll
    for (int mt = 0; mt < 4; ++mt)
      #pragma unroll
      for (int nt = 0; nt < 2; ++nt)
        acc2[mt][nt] = __builtin_amdgcn_mfma_f32_16x16x32_bf16(av[mt], bv[nt], acc2[mt][nt], 0, 0, 0);
  }

  // ---- fused layer 3: scores[m] = sum_n relu(h2[m][n]) * W3[n]  (+b3) ----
  {
    float b2v[2], w3v[2];
    #pragma unroll
    for (int nt = 0; nt < 2; ++nt) {
      int n2 = ng * 32 + nt * 16 + r16;
      b2v[nt] = b2[n2];
      w3v[nt] = w3[n2];
    }
    #pragma unroll
    for (int mt = 0; mt < 4; ++mt) {
      #pragma unroll
      for (int r = 0; r < 4; ++r) {
        float p = 0.f;
        #pragma unroll
        for (int nt = 0; nt < 2; ++nt) {
          float h = fmaxf(acc2[mt][nt][r] + b2v[nt], 0.f);
          p += h * w3v[nt];
        }
        // reduce over the 16 lanes of this quad-row (xor masks <16 stay in-group)
        p += __shfl_xor(p, 1);
        p += __shfl_xor(p, 2);
        p += __shfl_xor(p, 4);
        p += __shfl_xor(p, 8);
        if (r16 == 0) atomicAdd(&ss[mg * 64 + mt * 16 + q * 4 + r], p);
      }
    }
  }
  __syncthreads();

  if (tid < MT) {
    int g = row0 + tid;
    if (g < E) out[g] = ss[tid] + b3[0];
  }
}

extern "C" void kernel_launch(void* const* d_in, const int* in_sizes, int n_in,
                              void* d_out, int out_size, void* d_ws, size_t ws_size,
                              hipStream_t stream) {
  const float* x  = (const float*)d_in[0];
  const float* W1 = (const float*)d_in[1];
  const float* b1 = (const float*)d_in[2];
  const float* W2 = (const float*)d_in[3];
  const float* b2 = (const float*)d_in[4];
  const float* W3 = (const float*)d_in[5];
  const float* b3 = (const float*)d_in[6];
  // d_in[7] = edge_index (unused by the reference computation)
  const int*   ep = (const int*)d_in[8];
  float* out = (float*)d_out;

  const int NX = in_sizes[0];        // 100000*256 = 25,600,000
  const int E  = in_sizes[8] / 2;    // 1,000,000

  // workspace layout: xb (NX bf16) | w1t (256*256 bf16) | w2t (128*256 bf16)  ~49 MB
  unsigned short* xb  = (unsigned short*)d_ws;
  unsigned short* w1t = (unsigned short*)((char*)d_ws + (size_t)NX * 2);
  unsigned short* w2t = w1t + 256 * 256;

  cast_x_kernel<<<(NX / 4 + 255) / 256, 256, 0, stream>>>(x, xb, NX / 4);
  prep_w_kernel<<<(256 * 256 + 128 * 256 + 255) / 256, 256, 0, stream>>>(W1, W2, w1t, w2t);
  mlp_kernel<<<(E + MT - 1) / MT, NTHREADS, 0, stream>>>(xb, w1t, w2t, b1, b2, W3, b3, ep, out, E);
}

// Round 5
// 522.784 us; speedup vs baseline: 1.4188x; 1.2717x over previous
//
#include <hip/hip_runtime.h>

// PairwiseMLPLinkPredictor on MI355X (gfx950)
// feats = bf16(x[u]) * bf16(x[v]);  h1 = relu(feats@W1+b1);  h2 = relu(h1@W2+b2);
// out = h2@W3 + b3.
//
// R4b (R4 + compile fix): persistent blocks + software-pipelined double-buffered feats.
//  - block = 1024 thr (16 waves), MT=64 pairs/tile, 2x32KB LDS buffers (64 KB -> 2 blocks/CU)
//  - gather for tile t+1 register-staged during tile t's GEMMs (latency hidden)
//  - weight B-frags preloaded to registers BEFORE gather loads are issued, so
//    in-order vmcnt waits never drain the long-latency gather
//  - layer 3 via global atomicAdd into out pre-initialized to b3 (3 barriers/tile)

typedef __attribute__((ext_vector_type(8))) short short8;   // 8 bf16 = 4 VGPRs
typedef __attribute__((ext_vector_type(4))) float floatx4;  // MFMA C/D frag
typedef __attribute__((ext_vector_type(4))) unsigned uintx4;
typedef __attribute__((ext_vector_type(2))) int intx2;

#define MT 64         // pairs per tile
#define NTHREADS 1024 // 16 waves
#define NBLOCKS 512   // 2 blocks/CU resident

__device__ __forceinline__ unsigned short f2bf(float f) {
  union { float f; unsigned u; } a; a.f = f;
  unsigned r = a.u + 0x7FFFu + ((a.u >> 16) & 1u);   // RNE
  return (unsigned short)(r >> 16);
}

// packed bf16 x2 multiply via f32 (unpack, mul, RNE repack)
__device__ __forceinline__ unsigned bf16mul2(unsigned ua, unsigned ub) {
  float lo = __uint_as_float(ua << 16)          * __uint_as_float(ub << 16);
  float hi = __uint_as_float(ua & 0xFFFF0000u) * __uint_as_float(ub & 0xFFFF0000u);
  return (unsigned)f2bf(lo) | ((unsigned)f2bf(hi) << 16);
}

// ---------- prologue: x -> bf16 table ----------
__global__ void cast_x_kernel(const float* __restrict__ x, unsigned short* __restrict__ xb, int n4) {
  int i = blockIdx.x * blockDim.x + threadIdx.x;
  if (i >= n4) return;
  float4 v = ((const float4*)x)[i];
  ushort4 o;
  o.x = f2bf(v.x); o.y = f2bf(v.y); o.z = f2bf(v.z); o.w = f2bf(v.w);
  ((ushort4*)xb)[i] = o;
}

// ---------- prologue: W1 [256,256] / W2 [256,128] -> bf16, transposed to [n][k] ----------
__global__ void prep_w_kernel(const float* __restrict__ W1, const float* __restrict__ W2,
                              unsigned short* __restrict__ w1t, unsigned short* __restrict__ w2t) {
  int i = blockIdx.x * blockDim.x + threadIdx.x;
  if (i < 256 * 256) {
    int k = i >> 8, n = i & 255;
    w1t[n * 256 + k] = f2bf(W1[k * 256 + n]);
  } else {
    int j = i - 256 * 256;
    if (j < 128 * 256) {
      int k = j >> 7, n = j & 127;
      w2t[n * 256 + k] = f2bf(W2[k * 128 + n]);
    }
  }
}

// ---------- out[i] = b3 (scores accumulate via atomics) ----------
__global__ void init_out_kernel(float* __restrict__ out, const float* __restrict__ b3, int E) {
  int i = blockIdx.x * blockDim.x + threadIdx.x;
  if (i < E) out[i] = b3[0];
}

// ---------- fused pairwise MLP, persistent + pipelined ----------
__global__ __launch_bounds__(NTHREADS, 4) void mlp_kernel(
    const unsigned short* __restrict__ xb,
    const unsigned short* __restrict__ w1t,
    const unsigned short* __restrict__ w2t,
    const float* __restrict__ b1,
    const float* __restrict__ b2,
    const float* __restrict__ w3,
    const int* __restrict__ ep,
    float* __restrict__ out,
    int E)
{
  // 2 x (64 rows x 256 bf16) = 65536 B exactly -> 2 blocks/CU.
  // 16B chunks XOR-swizzled by (row & 15): conflict-free stride-512 ds_read_b128.
  __shared__ __align__(16) unsigned short buf[2][MT * 256];

  const int tid  = threadIdx.x;
  const int wv   = tid >> 6;      // 0..15
  const int lane = tid & 63;
  const int q    = lane >> 4;     // quad 0..3
  const int r16  = lane & 15;
  const int c    = tid & 31;      // 16B chunk within 512B row (staging)
  const int mr0  = tid >> 5;      // staging row base 0..31 (rows mr0, mr0+32)

  const int ntiles = (E + MT - 1) / MT;

  // ---- prologue: stage tile t0 into buf[0] ----
  {
    int t0 = blockIdx.x;
    #pragma unroll
    for (int s = 0; s < 2; ++s) {
      int m = mr0 + 32 * s;
      int g = t0 * MT + m; if (g >= E) g = E - 1;
      intx2 uv = __builtin_nontemporal_load((const intx2*)(ep + 2 * (size_t)g));
      uintx4 a = __builtin_nontemporal_load((const uintx4*)(xb + ((size_t)uv.x << 8) + (c << 3)));
      uintx4 b = __builtin_nontemporal_load((const uintx4*)(xb + ((size_t)uv.y << 8) + (c << 3)));
      uintx4 pv;
      #pragma unroll
      for (int tt = 0; tt < 4; ++tt) pv[tt] = bf16mul2(a[tt], b[tt]);
      *(uintx4*)((char*)buf[0] + m * 512 + ((c ^ (m & 15)) << 4)) = pv;
    }
  }
  __syncthreads();

  int p = 0;
  for (int t = blockIdx.x; t < ntiles; t += NBLOCKS) {
    char* const bufp = (char*)buf[p];
    char* const bufn = (char*)buf[p ^ 1];
    const int tn = (t + NBLOCKS < ntiles) ? (t + NBLOCKS) : t;

    // ---- (1) prefetch ep indices for next tile (deepest in vmem queue) ----
    intx2 uvn[2];
    #pragma unroll
    for (int s = 0; s < 2; ++s) {
      int g = tn * MT + mr0 + 32 * s; if (g >= E) g = E - 1;
      uvn[s] = __builtin_nontemporal_load((const intx2*)(ep + 2 * (size_t)g));
    }

    // ---- (2) GEMM1: wave owns 64 rows x 16 cols (n = wv*16 + r16) ----
    const unsigned short* const b1p = w1t + (wv * 16 + r16) * 256 + q * 8;
    short8 bv1[8];
    #pragma unroll
    for (int kt = 0; kt < 8; ++kt) bv1[kt] = *(const short8*)(b1p + kt * 32);

    floatx4 acc[4];
    #pragma unroll
    for (int i = 0; i < 4; ++i) acc[i] = (floatx4){0.f, 0.f, 0.f, 0.f};

    char* const a1base = bufp + r16 * 512;
    #pragma unroll
    for (int kt = 0; kt < 8; ++kt) {
      const int aoff = (kt << 6) ^ ((q ^ r16) << 4);
      short8 av[4];
      #pragma unroll
      for (int mt = 0; mt < 4; ++mt)
        av[mt] = *(const short8*)(a1base + mt * (16 * 512) + aoff);
      #pragma unroll
      for (int mt = 0; mt < 4; ++mt)
        acc[mt] = __builtin_amdgcn_mfma_f32_16x16x32_bf16(av[mt], bv1[kt], acc[mt], 0, 0, 0);
    }
    __syncthreads();   // all waves done reading feats in bufp

    // ---- (3) h1 writeback (bias+relu, bf16) into bufp, swizzled ----
    {
      const int n1 = wv * 16 + r16;
      const float bias1 = b1[n1];
      #pragma unroll
      for (int mt = 0; mt < 4; ++mt) {
        #pragma unroll
        for (int r = 0; r < 4; ++r) {
          int m = mt * 16 + q * 4 + r;            // C/D: row = 4*quad + reg
          float h = fmaxf(acc[mt][r] + bias1, 0.f);
          int ch = (n1 >> 3) ^ (m & 15);
          *(unsigned short*)(bufp + m * 512 + (ch << 4) + ((n1 & 7) << 1)) = f2bf(h);
        }
      }
    }
    __syncthreads();   // h1 ready

    // ---- (4) preload GEMM2 B-frags, THEN issue next-tile gather loads ----
    const int mg2 = wv >> 3;        // 0..1: 32-row slab
    const int ng2 = wv & 7;         // 0..7: 16-col slab
    const unsigned short* const b2p = w2t + (ng2 * 16 + r16) * 256 + q * 8;
    short8 bv2[8];
    #pragma unroll
    for (int kt = 0; kt < 8; ++kt) bv2[kt] = *(const short8*)(b2p + kt * 32);

    uintx4 ra[2], rb[2];
    #pragma unroll
    for (int s = 0; s < 2; ++s) {
      ra[s] = __builtin_nontemporal_load((const uintx4*)(xb + ((size_t)uvn[s].x << 8) + (c << 3)));
      rb[s] = __builtin_nontemporal_load((const uintx4*)(xb + ((size_t)uvn[s].y << 8) + (c << 3)));
    }

    // ---- (5) GEMM2: wave owns 32 rows x 16 cols; K=256 ----
    floatx4 acc2[2];
    acc2[0] = (floatx4){0.f, 0.f, 0.f, 0.f};
    acc2[1] = (floatx4){0.f, 0.f, 0.f, 0.f};
    char* const a2base = bufp + (mg2 * 32 + r16) * 512;
    #pragma unroll
    for (int kt = 0; kt < 8; ++kt) {
      const int aoff = (kt << 6) ^ ((q ^ r16) << 4);
      short8 av0 = *(const short8*)(a2base + aoff);
      short8 av1 = *(const short8*)(a2base + 16 * 512 + aoff);
      acc2[0] = __builtin_amdgcn_mfma_f32_16x16x32_bf16(av0, bv2[kt], acc2[0], 0, 0, 0);
      acc2[1] = __builtin_amdgcn_mfma_f32_16x16x32_bf16(av1, bv2[kt], acc2[1], 0, 0, 0);
    }

    // ---- (6) fused layer 3: out[g] += sum_n relu(h2)*W3  (out pre-init to b3) ----
    {
      const int n2 = ng2 * 16 + r16;
      const float b2v = b2[n2];
      const float w3v = w3[n2];
      #pragma unroll
      for (int mt = 0; mt < 2; ++mt) {
        #pragma unroll
        for (int r = 0; r < 4; ++r) {
          float h = fmaxf(acc2[mt][r] + b2v, 0.f);
          float pp = h * w3v;
          pp += __shfl_xor(pp, 1);
          pp += __shfl_xor(pp, 2);
          pp += __shfl_xor(pp, 4);
          pp += __shfl_xor(pp, 8);
          if (r16 == 0) {
            int g = t * MT + mg2 * 32 + mt * 16 + q * 4 + r;
            if (g < E) atomicAdd(out + g, pp);
          }
        }
      }
    }

    // ---- (7) convert + store staged feats for next tile into bufn ----
    #pragma unroll
    for (int s = 0; s < 2; ++s) {
      int m = mr0 + 32 * s;
      uintx4 pv;
      #pragma unroll
      for (int tt = 0; tt < 4; ++tt) pv[tt] = bf16mul2(ra[s][tt], rb[s][tt]);
      *(uintx4*)(bufn + m * 512 + ((c ^ (m & 15)) << 4)) = pv;
    }
    __syncthreads();   // next feats ready
    p ^= 1;
  }
}

extern "C" void kernel_launch(void* const* d_in, const int* in_sizes, int n_in,
                              void* d_out, int out_size, void* d_ws, size_t ws_size,
                              hipStream_t stream) {
  const float* x  = (const float*)d_in[0];
  const float* W1 = (const float*)d_in[1];
  const float* b1 = (const float*)d_in[2];
  const float* W2 = (const float*)d_in[3];
  const float* b2 = (const float*)d_in[4];
  const float* W3 = (const float*)d_in[5];
  const float* b3 = (const float*)d_in[6];
  // d_in[7] = edge_index (unused by the reference computation)
  const int*   ep = (const int*)d_in[8];
  float* out = (float*)d_out;

  const int NX = in_sizes[0];        // 100000*256 = 25,600,000
  const int E  = in_sizes[8] / 2;    // 1,000,000

  // workspace layout: xb (NX bf16) | w1t (256*256 bf16) | w2t (128*256 bf16)  ~49 MB
  unsigned short* xb  = (unsigned short*)d_ws;
  unsigned short* w1t = (unsigned short*)((char*)d_ws + (size_t)NX * 2);
  unsigned short* w2t = w1t + 256 * 256;

  init_out_kernel<<<(E + 255) / 256, 256, 0, stream>>>(out, b3, E);
  cast_x_kernel<<<(NX / 4 + 255) / 256, 256, 0, stream>>>(x, xb, NX / 4);
  prep_w_kernel<<<(256 * 256 + 128 * 256 + 255) / 256, 256, 0, stream>>>(W1, W2, w1t, w2t);
  mlp_kernel<<<NBLOCKS, NTHREADS, 0, stream>>>(xb, w1t, w2t, b1, b2, W3, ep, out, E);
}